// Round 7
// baseline (85.589 us; speedup 1.0000x reference)
//
#include <hip/hip_runtime.h>
#include <math.h>

#define N_MID 62
#define BATCH 32768

typedef float f32x4 __attribute__((ext_vector_type(4)));
typedef short s16x8 __attribute__((ext_vector_type(8)));
typedef unsigned int u32x4 __attribute__((ext_vector_type(4)));

// fp32 -> bf16 round-half-up (prefix only; inputs positive finite)
__device__ __forceinline__ short f2bf(float f) {
    unsigned u = __float_as_uint(f);
    return (short)((u + 0x8000u) >> 16);
}

// ---- Prefix: t_mid fp32 -> bf16 A-frags with component relabeling ----------
// Frag f = (site*2 + branch)*2 + tile. MFMA A-layout (16x16x32):
// lane l holds A[m=l&15][k=(l>>4)*8+j]; we store A_t[m,k] = T[lam(k)][16t+m],
// lam(8q+j) = 16*(j>>2) + 4q + (j&3), making the C->B transform in-lane.
__global__ __launch_bounds__(64) void prefix_kernel(const float* __restrict__ t_mid,
                                                    short* __restrict__ wsA) {
    int f = blockIdx.x;              // 0..247
    int l = threadIdx.x;
    int t = f & 1, b = (f >> 1) & 1, s = f >> 2;
    int q = l >> 4, m = l & 15;
    const float* src = t_mid + (size_t)(s * 2 + b) * 1024;  // T[k][n] 32x32
    s16x8 v;
    #pragma unroll
    for (int j = 0; j < 8; ++j) {
        int lam = 16 * (j >> 2) + 4 * q + (j & 3);
        v[j] = f2bf(src[lam * 32 + 16 * t + m]);
    }
    ((s16x8*)wsA)[f * 64 + l] = v;
}

// ---------------------------- Main MFMA kernel -----------------------------
// One wave = 32 batch elements = TWO B-fragments (groups A/B) sharing the
// same 4 A-frags (2 branches x 2 col-tiles) -> matrix fetch per element
// halves vs 1 group. No LDS, no barriers. Per site: 8 MFMAs; per-group
// in-lane branch select (8 cndmask) + pack (4 v_perm); A-frags prefetched
// 4 sites ahead (over-reads past wsA stay inside the 256 MiB d_ws).
__global__ __launch_bounds__(256, 1) void mps_mfma_kernel(
    const float* __restrict__ t_first,
    const float* __restrict__ t_last,
    const int*   __restrict__ x,
    const short* __restrict__ wsA,
    float* __restrict__ out)
{
    const int tid  = threadIdx.x;
    const int w    = tid >> 6;
    const int l    = tid & 63;
    const int q    = l >> 4;
    const int e    = l & 15;
    const int base = (blockIdx.x * 4 + w) * 32;

    // ---- Inline spin mask for an element: bit s = (x[elem][s] > 0). ----
    auto build_mask = [&](int elem) -> unsigned long long {
        const int4* xr = (const int4*)(x + (size_t)elem * 64 + 16 * q);
        unsigned chunk = 0;
        #pragma unroll
        for (int c = 0; c < 4; ++c) {
            int4 v = xr[c];
            chunk |= (unsigned)(v.x > 0) << (4 * c + 0);
            chunk |= (unsigned)(v.y > 0) << (4 * c + 1);
            chunk |= (unsigned)(v.z > 0) << (4 * c + 2);
            chunk |= (unsigned)(v.w > 0) << (4 * c + 3);
        }
        unsigned sh = chunk << ((q & 1) * 16);
        unsigned lo = (q < 2) ? sh : 0u;
        unsigned hi = (q >= 2) ? sh : 0u;
        lo |= (unsigned)__shfl_xor((int)lo, 16);
        lo |= (unsigned)__shfl_xor((int)lo, 32);
        hi |= (unsigned)__shfl_xor((int)hi, 16);
        hi |= (unsigned)__shfl_xor((int)hi, 32);
        return ((unsigned long long)hi << 32) | lo;
    };
    unsigned long long mrotA = build_mask(base + e);
    unsigned long long mrotB = build_mask(base + 16 + e);

    // ---- Init states as B-frags from t_first[bit0]. ----
    float stA[8], stB[8];
    {
        const float* tfA = t_first + ((mrotA & 1ull) ? 32 : 0);
        const float* tfB = t_first + ((mrotB & 1ull) ? 32 : 0);
        #pragma unroll
        for (int j = 0; j < 8; ++j) {
            int c = 16 * (j >> 2) + 4 * q + (j & 3);
            stA[j] = tfA[c];
            stB[j] = tfB[c];
        }
    }
    mrotA >>= 1;
    mrotB >>= 1;

    s16x8 BstA, BstB;
    auto packB = [&](const float* st) -> s16x8 {
        u32x4 bp;
        #pragma unroll
        for (int d = 0; d < 4; ++d)
            bp[d] = __builtin_amdgcn_perm(__float_as_uint(st[2 * d + 1]),
                                          __float_as_uint(st[2 * d]), 0x07060302u);
        return __builtin_bit_cast(s16x8, bp);
    };
    BstA = packB(stA);
    BstB = packB(stB);

    int expA = 0, expB = 0;
    const f32x4 cz = {0.f, 0.f, 0.f, 0.f};

    // A-frag slots: 4-site-deep rolling prefetch.
    const s16x8* pA = (const s16x8*)wsA + l;  // frag idx = site*4 + f
    s16x8 A[4][4];
    #pragma unroll
    for (int sl = 0; sl < 4; ++sl)
        #pragma unroll
        for (int f = 0; f < 4; ++f)
            A[sl][f] = pA[(sl * 4 + f) * 64];
    const s16x8* pp = pA + 16 * 64;  // site-4 frags

    auto site = [&](s16x8* A4, const s16x8* pf, bool resc) {
        f32x4 ya00 = __builtin_amdgcn_mfma_f32_16x16x32_bf16(A4[0], BstA, cz, 0, 0, 0);
        f32x4 ya01 = __builtin_amdgcn_mfma_f32_16x16x32_bf16(A4[1], BstA, cz, 0, 0, 0);
        f32x4 ya10 = __builtin_amdgcn_mfma_f32_16x16x32_bf16(A4[2], BstA, cz, 0, 0, 0);
        f32x4 ya11 = __builtin_amdgcn_mfma_f32_16x16x32_bf16(A4[3], BstA, cz, 0, 0, 0);
        f32x4 yb00 = __builtin_amdgcn_mfma_f32_16x16x32_bf16(A4[0], BstB, cz, 0, 0, 0);
        f32x4 yb01 = __builtin_amdgcn_mfma_f32_16x16x32_bf16(A4[1], BstB, cz, 0, 0, 0);
        f32x4 yb10 = __builtin_amdgcn_mfma_f32_16x16x32_bf16(A4[2], BstB, cz, 0, 0, 0);
        f32x4 yb11 = __builtin_amdgcn_mfma_f32_16x16x32_bf16(A4[3], BstB, cz, 0, 0, 0);

        if (pf) {  // refill this slot with site s+4 (over-read safe in d_ws)
            #pragma unroll
            for (int f = 0; f < 4; ++f) A4[f] = pf[f * 64];
        }

        bool hiA = (mrotA & 1ull) != 0; mrotA >>= 1;
        bool hiB = (mrotB & 1ull) != 0; mrotB >>= 1;
        #pragma unroll
        for (int r = 0; r < 4; ++r) {
            stA[r]     = hiA ? ya10[r] : ya00[r];
            stA[4 + r] = hiA ? ya11[r] : ya01[r];
            stB[r]     = hiB ? yb10[r] : yb00[r];
            stB[4 + r] = hiB ? yb11[r] : yb01[r];
        }

        if (resc) {  // per-element pow2 rescale, exact log bookkeeping
            float mxA = stA[0], mxB = stB[0];
            #pragma unroll
            for (int j = 1; j < 8; ++j) { mxA = fmaxf(mxA, stA[j]); mxB = fmaxf(mxB, stB[j]); }
            mxA = fmaxf(mxA, __shfl_xor(mxA, 16)); mxA = fmaxf(mxA, __shfl_xor(mxA, 32));
            mxB = fmaxf(mxB, __shfl_xor(mxB, 16)); mxB = fmaxf(mxB, __shfl_xor(mxB, 32));
            int exA = (int)((__float_as_uint(mxA) >> 23) & 0xFF) - 127;
            int exB = (int)((__float_as_uint(mxB) >> 23) & 0xFF) - 127;
            float scA = __uint_as_float((unsigned)(127 - exA) << 23);
            float scB = __uint_as_float((unsigned)(127 - exB) << 23);
            #pragma unroll
            for (int j = 0; j < 8; ++j) { stA[j] *= scA; stB[j] *= scB; }
            expA += exA; expB += exB;
        }

        BstA = packB(stA);
        BstB = packB(stB);
    };

    for (int k = 0; k < 15; ++k) {  // sites 4k..4k+3; rescale at s=7,15,..,55
        #pragma unroll
        for (int sl = 0; sl < 4; ++sl) {
            site(A[sl], pp, (sl == 3) && (k & 1));
            pp += 4 * 64;
        }
    }
    site(A[0], nullptr, false);  // site 60
    site(A[1], nullptr, false);  // site 61

    // ---- Epilogue: amp = dot(state, t_last[bit63]); reduce over q. ----
    const float* tlA = t_last + ((mrotA & 1ull) ? 32 : 0);
    const float* tlB = t_last + ((mrotB & 1ull) ? 32 : 0);
    float ampA = 0.f, ampB = 0.f;
    #pragma unroll
    for (int j = 0; j < 8; ++j) {
        int c = 16 * (j >> 2) + 4 * q + (j & 3);
        ampA = fmaf(stA[j], tlA[c], ampA);
        ampB = fmaf(stB[j], tlB[c], ampB);
    }
    ampA += __shfl_xor(ampA, 16); ampA += __shfl_xor(ampA, 32);
    ampB += __shfl_xor(ampB, 16); ampB += __shfl_xor(ampB, 32);

    if (l < 16) {
        out[base + l]      = logf(ampA) + 0.69314718055994531f * (float)expA;
        out[base + 16 + l] = logf(ampB) + 0.69314718055994531f * (float)expB;
    }
}

extern "C" void kernel_launch(void* const* d_in, const int* in_sizes, int n_in,
                              void* d_out, int out_size, void* d_ws, size_t ws_size,
                              hipStream_t stream) {
    const float* t_first = (const float*)d_in[0];
    const float* t_mid   = (const float*)d_in[1];
    const float* t_last  = (const float*)d_in[2];
    const int*   x       = (const int*)d_in[3];
    float* out           = (float*)d_out;

    short* wsA = (short*)d_ws;  // 248 KB of bf16 A-frags

    hipLaunchKernelGGL(prefix_kernel, dim3(N_MID * 4), dim3(64), 0, stream, t_mid, wsA);
    hipLaunchKernelGGL(mps_mfma_kernel, dim3(BATCH / 128), dim3(256), 0, stream,
                       t_first, t_last, x, wsA, out);
}

// Round 8
// 77.698 us; speedup vs baseline: 1.1016x; 1.1016x over previous
//
#include <hip/hip_runtime.h>
#include <math.h>

#define N_MID 62
#define NPAIR 31
#define BATCH 32768

typedef float f32x4 __attribute__((ext_vector_type(4)));
typedef unsigned int u32x2 __attribute__((ext_vector_type(2)));
typedef unsigned int u32x4 __attribute__((ext_vector_type(4)));

__device__ __forceinline__ long mklong(unsigned a, unsigned b) {
    u32x2 t = {a, b};
    return __builtin_bit_cast(long, t);
}
// pack 4 fp32 -> dword of 4 fp8 e4m3 (bytes 0..3 = a,b,c,d)
__device__ __forceinline__ unsigned pack_fp8x4(float a, float b, float c, float d) {
    int r = __builtin_amdgcn_cvt_pk_fp8_f32(a, b, 0, false);
    r = __builtin_amdgcn_cvt_pk_fp8_f32(c, d, r, true);
    return (unsigned)r;
}

// ---- Prefix: site-pair products T[2i][v0]*T[2i+1][v1] as fp8 A-frags ------
// Block = (pair i)*4 + variant v (v0=v&1 site 2i, v1=v>>1 site 2i+1).
// MFMA fp8 16x16x32 A-layout: lane l holds A[m=l&15][k=(l>>4)*8+j] in byte j.
// We store A_t[m,k] = P[lam(k)][16t+m], lam(8q+j)=16*(j>>2)+4q+(j&3), so the
// main loop's D->B handoff is purely in-lane (slot j=4t+r <- y_t[r]).
__global__ __launch_bounds__(64) void prefix_kernel(const float* __restrict__ t_mid,
                                                    unsigned* __restrict__ wsP) {
    __shared__ float M1s[1024], M2s[1024];
    const int l = threadIdx.x, q = l >> 4, m = l & 15;
    const int i = blockIdx.x >> 2, v = blockIdx.x & 3;

    const float4* s1 = (const float4*)(t_mid + (size_t)((2 * i) * 2 + (v & 1)) * 1024);
    const float4* s2 = (const float4*)(t_mid + (size_t)((2 * i + 1) * 2 + (v >> 1)) * 1024);
    #pragma unroll
    for (int c = 0; c < 4; ++c) {
        ((float4*)M1s)[c * 64 + l] = s1[c * 64 + l];
        ((float4*)M2s)[c * 64 + l] = s2[c * 64 + l];
    }
    __syncthreads();

    // cache this lane's two output columns of M2
    float colv[2][32];
    #pragma unroll
    for (int t = 0; t < 2; ++t)
        #pragma unroll
        for (int mm = 0; mm < 32; ++mm)
            colv[t][mm] = M2s[mm * 32 + 16 * t + m];

    float o0[8], o1[8];  // tile0/tile1, byte j
    #pragma unroll
    for (int j = 0; j < 8; ++j) {
        int a = 16 * (j >> 2) + 4 * q + (j & 3);  // lam(8q+j)
        float acc0 = 0.f, acc1 = 0.f;
        #pragma unroll
        for (int mm = 0; mm < 32; ++mm) {
            float r = M1s[a * 32 + mm];
            acc0 = fmaf(r, colv[0][mm], acc0);
            acc1 = fmaf(r, colv[1][mm], acc1);
        }
        o0[j] = acc0;
        o1[j] = acc1;
    }

    u32x4 outw;
    outw[0] = pack_fp8x4(o0[0], o0[1], o0[2], o0[3]);
    outw[1] = pack_fp8x4(o0[4], o0[5], o0[6], o0[7]);
    outw[2] = pack_fp8x4(o1[0], o1[1], o1[2], o1[3]);
    outw[3] = pack_fp8x4(o1[4], o1[5], o1[6], o1[7]);
    ((u32x4*)wsP)[blockIdx.x * 64 + l] = outw;
}

// ---------------------------- Main MFMA kernel -----------------------------
// One wave = 16 batch elements (element = lane&15), no LDS, no barriers.
// State = fp8 B-frag (2 dwords): byte j of lane (q,e) holds component
// lam(8q+j) of element e. Per pair-step: 4 per-element-masked B copies
// (variant = 2 spin bits), 8 accumulating fp8 MFMAs (4 variants x 2 tiles),
// pow2 rescale every step (exact log bookkeeping), repack to fp8.
__global__ __launch_bounds__(256, 2) void mps_mfma_kernel(
    const float* __restrict__ t_first,
    const float* __restrict__ t_last,
    const int*   __restrict__ x,
    const unsigned* __restrict__ wsP,
    float* __restrict__ out)
{
    const int tid  = threadIdx.x;
    const int w    = tid >> 6;
    const int l    = tid & 63;
    const int q    = l >> 4;
    const int e    = l & 15;
    const int base = (blockIdx.x * 4 + w) * 16;

    // ---- Inline spin mask for element e: bit s = (x[base+e][s] > 0). ----
    unsigned long long mrot;
    {
        const int4* xr = (const int4*)(x + (size_t)(base + e) * 64 + 16 * q);
        unsigned chunk = 0;
        #pragma unroll
        for (int c = 0; c < 4; ++c) {
            int4 vv = xr[c];
            chunk |= (unsigned)(vv.x > 0) << (4 * c + 0);
            chunk |= (unsigned)(vv.y > 0) << (4 * c + 1);
            chunk |= (unsigned)(vv.z > 0) << (4 * c + 2);
            chunk |= (unsigned)(vv.w > 0) << (4 * c + 3);
        }
        unsigned sh = chunk << ((q & 1) * 16);
        unsigned lo = (q < 2) ? sh : 0u;
        unsigned hi = (q >= 2) ? sh : 0u;
        lo |= (unsigned)__shfl_xor((int)lo, 16);
        lo |= (unsigned)__shfl_xor((int)lo, 32);
        hi |= (unsigned)__shfl_xor((int)hi, 16);
        hi |= (unsigned)__shfl_xor((int)hi, 32);
        unsigned long long mask = ((unsigned long long)hi << 32) | lo;
        // init state below uses bit0; pairs consume bits 1..62; bit63 = t_last
        const float* tf = t_first + ((mask & 1ull) ? 32 : 0);
        mrot = mask >> 1;
        (void)tf;
    }

    // ---- Init state (B-frag component order) from t_first[bit0]. ----
    float st[8];
    {
        // recompute tf cheaply (bit0 consumed above): bit0 = x[base+e][0] > 0
        // (mask>>1 already applied; recover from x directly)
        const float* tf = t_first + ((x[(size_t)(base + e) * 64] > 0) ? 32 : 0);
        #pragma unroll
        for (int j = 0; j < 8; ++j)
            st[j] = tf[16 * (j >> 2) + 4 * q + (j & 3)];
    }
    unsigned Bd0 = pack_fp8x4(st[0], st[1], st[2], st[3]);
    unsigned Bd1 = pack_fp8x4(st[4], st[5], st[6], st[7]);

    int expsum = 0;
    const f32x4 cz = {0.f, 0.f, 0.f, 0.f};

    // 2-step rolling prefetch of pair-frags: 4 variants x 16 B/lane per step.
    const u32x4* W = (const u32x4*)wsP + l;  // step i, variant v: + (i*4+v)*64
    u32x4 Q0[4], Q1[4];
    #pragma unroll
    for (int v = 0; v < 4; ++v) Q0[v] = W[v * 64];
    #pragma unroll
    for (int v = 0; v < 4; ++v) Q1[v] = W[(4 + v) * 64];

    auto step = [&](u32x4* Q, const u32x4* pf) {
        // variant index for this element = next 2 spin bits
        unsigned vl = (unsigned)mrot & 3u;
        mrot >>= 2;

        f32x4 y0 = cz, y1 = cz;
        #pragma unroll
        for (int v = 0; v < 4; ++v) {
            long A0 = mklong(Q[v][0], Q[v][1]);   // tile 0
            long A1 = mklong(Q[v][2], Q[v][3]);   // tile 1
            bool sel = (vl == (unsigned)v);
            long u = mklong(sel ? Bd0 : 0u, sel ? Bd1 : 0u);
            y0 = __builtin_amdgcn_mfma_f32_16x16x32_fp8_fp8(A0, u, y0, 0, 0, 0);
            y1 = __builtin_amdgcn_mfma_f32_16x16x32_fp8_fp8(A1, u, y1, 0, 0, 0);
        }

        if (pf) {
            #pragma unroll
            for (int v = 0; v < 4; ++v) Q[v] = pf[v * 64];
        }

        #pragma unroll
        for (int r = 0; r < 4; ++r) { st[r] = y0[r]; st[4 + r] = y1[r]; }

        // per-element pow2 rescale (keeps fp8 pack in range; exact log)
        float mx = st[0];
        #pragma unroll
        for (int j = 1; j < 8; ++j) mx = fmaxf(mx, st[j]);
        mx = fmaxf(mx, __shfl_xor(mx, 16));
        mx = fmaxf(mx, __shfl_xor(mx, 32));
        int ex = (int)((__float_as_uint(mx) >> 23) & 0xFF) - 127;
        float sc = __uint_as_float((unsigned)(127 - ex) << 23);
        #pragma unroll
        for (int j = 0; j < 8; ++j) st[j] *= sc;
        expsum += ex;

        Bd0 = pack_fp8x4(st[0], st[1], st[2], st[3]);
        Bd1 = pack_fp8x4(st[4], st[5], st[6], st[7]);
    };

    const u32x4* pf = W + 8 * 64;  // step-2 frags
    for (int k = 0; k < 15; ++k) {
        step(Q0, pf);                              // step 2k
        step(Q1, (k < 14) ? pf + 4 * 64 : nullptr); // step 2k+1
        pf += 8 * 64;
    }
    step(Q0, nullptr);  // step 30

    // ---- Epilogue: amp = dot(state, t_last[bit63]); reduce over q. ----
    const float* tl = t_last + ((mrot & 1ull) ? 32 : 0);
    float amp = 0.f;
    #pragma unroll
    for (int j = 0; j < 8; ++j)
        amp = fmaf(st[j], tl[16 * (j >> 2) + 4 * q + (j & 3)], amp);
    amp += __shfl_xor(amp, 16);
    amp += __shfl_xor(amp, 32);

    if (l < 16)
        out[base + l] = logf(amp) + 0.69314718055994531f * (float)expsum;
}

extern "C" void kernel_launch(void* const* d_in, const int* in_sizes, int n_in,
                              void* d_out, int out_size, void* d_ws, size_t ws_size,
                              hipStream_t stream) {
    const float* t_first = (const float*)d_in[0];
    const float* t_mid   = (const float*)d_in[1];
    const float* t_last  = (const float*)d_in[2];
    const int*   x       = (const int*)d_in[3];
    float* out           = (float*)d_out;

    unsigned* wsP = (unsigned*)d_ws;  // 31 pairs x 4 variants x 1 KB = 124 KB

    hipLaunchKernelGGL(prefix_kernel, dim3(NPAIR * 4), dim3(64), 0, stream, t_mid, wsP);
    hipLaunchKernelGGL(mps_mfma_kernel, dim3(BATCH / 64), dim3(256), 0, stream,
                       t_first, t_last, x, wsP, out);
}